// Round 10
// baseline (348.365 us; speedup 1.0000x reference)
//
#include <hip/hip_runtime.h>
#include <stdint.h>

typedef __attribute__((ext_vector_type(8))) short short8;
typedef __attribute__((ext_vector_type(4))) float f32x4;
typedef __attribute__((ext_vector_type(4))) unsigned short us4;

#define DI __device__ __forceinline__

static constexpr int Dm = 1024;   // hidden dim
static constexpr int Sm = 4096;   // latent tokens
static constexpr int Em = 160;    // encoder tokens
static constexpr int Hm = 16;     // heads

// workspace layout (bytes)
static constexpr size_t OFF_HSB  = 0;           // hs bf16 [8*4096][1024] (stays live: O-proj resid)
static constexpr size_t OFF_WT   = 67108864;    // 4x Wt bf16 [1024][1024] (transposed: [N][K])
static constexpr size_t OFF_QB   = 75497472;    // Q bf16 [8*4096][1024]; attn overwrites IN-PLACE with attn-out
static constexpr size_t OFF_KB   = 142606336;   // K bf16 [8*160][1024]
static constexpr size_t OFF_VT   = 147849216;   // V^T bf16 [8][16][64][192]
static constexpr size_t OFF_EHSB = 150994944;   // ehs bf16 [8*160][1024]

DI unsigned short f2b(float f) {
  union { float f; unsigned u; } x; x.f = f;
  unsigned r = x.u + 0x7fffu + ((x.u >> 16) & 1u);
  return (unsigned short)(r >> 16);
}

DI float b2f(unsigned short h) {
  union { unsigned u; float f; } x; x.u = ((unsigned)h) << 16; return x.f;
}

DI void gl_lds16(const void* g, void* l) {
  __builtin_amdgcn_global_load_lds(
      (const __attribute__((address_space(1))) unsigned int*)g,
      (__attribute__((address_space(3))) unsigned int*)l, 16, 0, 0);
}

// ---------------- prep: W transpose+cvt || ehs cvt || hs cvt (one launch) ----------------
// bid <  4096            : Wq/Wk/Wv/Wo [K][N] fp32 -> Wt [N][K] bf16
// 4096 <= bid < 5376     : ehs cvt (1280 blocks exactly cover 8*160*1024)
// 5376 <= bid < 7424     : hs cvt (2048 blocks x 16 iters)
__global__ void k_prep(const float* __restrict__ ehs, unsigned short* __restrict__ eb,
                       const float* __restrict__ hs, unsigned short* __restrict__ hsb,
                       const float* __restrict__ W0, const float* __restrict__ W1,
                       const float* __restrict__ W2, const float* __restrict__ W3,
                       unsigned short* __restrict__ Wt) {
  __shared__ float t[32][33];
  const int bid = blockIdx.x, tid = threadIdx.x;
  if (bid < 4096) {
    const int bz = bid >> 10, rest = bid & 1023, by = rest >> 5, bx = rest & 31;
    const float* W = (bz == 0) ? W0 : (bz == 1) ? W1 : (bz == 2) ? W2 : W3;
    unsigned short* o = Wt + (size_t)bz * 1048576;
    const int tx = tid & 31, ty = tid >> 5;
    const int n = bx * 32 + tx, k0 = by * 32;
    #pragma unroll
    for (int j = ty; j < 32; j += 8) t[j][tx] = W[(size_t)(k0 + j) * 1024 + n];
    __syncthreads();
    #pragma unroll
    for (int j = ty; j < 32; j += 8)
      o[(size_t)(bx * 32 + j) * 1024 + k0 + tx] = f2b(t[tx][j]);
  } else if (bid < 5376) {
    const int i = (bid - 4096) * 256 + tid;
    float4 v = ((const float4*)ehs)[i];
    us4 o = { f2b(v.x), f2b(v.y), f2b(v.z), f2b(v.w) };
    *(us4*)(eb + (size_t)i * 4) = o;
  } else {
    for (int i = (bid - 5376) * 256 + tid; i < 8388608; i += 2048 * 256) {
      float4 v = ((const float4*)hs)[i];
      us4 o = { f2b(v.x), f2b(v.y), f2b(v.z), f2b(v.w) };
      *(us4*)(hsb + (size_t)i * 4) = o;
    }
  }
}

// ---------------- fused Q + K + V projection GEMM (one launch) ----------------
// bid < 160 : kv blocks (dispatched FIRST so they finish early):
//   z = bid/80 (0:K, 1:V); A = eb [1280][1024]; K -> kb bf16; V -> TRANSPOSED vt.
// bid >= 160: Q blocks (q = bid-160, 2048 of them), m97-class 128x128 body,
//   co-residency decode (160%8==0 so q&7 is still the XCD), A = hsb, C = qb bf16
//   via LDS-staged coalesced epilogue with NON-TEMPORAL stores (keep L2 for A/B).
__global__ __launch_bounds__(256, 2) void k_gemm_qkv(const unsigned short* __restrict__ hsb,
                                                     const unsigned short* __restrict__ eb,
                                                     const unsigned short* __restrict__ Wt,
                                                     unsigned short* __restrict__ qb,
                                                     unsigned short* __restrict__ kb,
                                                     unsigned short* __restrict__ vt) {
  __shared__ __align__(16) char smem[32768];
  char* As = smem;
  char* Bs = smem + 16384;
  const int bid = blockIdx.x, tid = threadIdx.x;
  const int lane = tid & 63;
  const int l15 = lane & 15;
  const int g = lane >> 4;
  const int wv = tid >> 6;
  const int wr = wv >> 1, wc = wv & 1;

  const bool isKV = (bid < 160);
  int m0, n0;
  const unsigned short *Ap, *Bt;
  if (isKV) {
    const int z = bid / 80, rr = bid - z * 80;
    m0 = (rr % 10) * 128; n0 = (rr / 10) * 128;
    Ap = eb; Bt = Wt + (size_t)(1 + z) * 1048576;
  } else {
    const int q = bid - 160;
    m0 = ((q >> 6) * 8 + (q & 7)) * 128;
    n0 = ((q >> 3) & 7) * 128;
    Ap = hsb; Bt = Wt;
  }

  f32x4 acc[4][4];
  #pragma unroll
  for (int i = 0; i < 4; ++i)
    #pragma unroll
    for (int j = 0; j < 4; ++j) acc[i][j] = (f32x4){0.f, 0.f, 0.f, 0.f};

  for (int t = 0; t < 16; ++t) {
    __syncthreads();
    #pragma unroll
    for (int is = 0; is < 4; ++is) {
      int ch = is * 256 + tid;
      int row = ch >> 3, j = ch & 7;
      int sj = (j ^ (row & 7)) * 8;
      gl_lds16(Ap + (size_t)(m0 + row) * 1024 + t * 64 + sj, As + ch * 16);
      gl_lds16(Bt + (size_t)(n0 + row) * 1024 + t * 64 + sj, Bs + ch * 16);
    }
    __syncthreads();
    short8 af[2][4], bf[2][4];
    #pragma unroll
    for (int kk = 0; kk < 2; ++kk)
      #pragma unroll
      for (int mt = 0; mt < 4; ++mt) {
        af[kk][mt] = *(const short8*)(As + (wr * 64 + mt * 16 + l15) * 128 + ((kk * 64 + g * 16) ^ ((l15 & 7) << 4)));
        bf[kk][mt] = *(const short8*)(Bs + (wc * 64 + mt * 16 + l15) * 128 + ((kk * 64 + g * 16) ^ ((l15 & 7) << 4)));
      }
    #pragma unroll
    for (int kk = 0; kk < 2; ++kk)
      #pragma unroll
      for (int mt = 0; mt < 4; ++mt)
        #pragma unroll
        for (int nt = 0; nt < 4; ++nt)
          acc[mt][nt] = __builtin_amdgcn_mfma_f32_16x16x32_bf16(af[kk][mt], bf[kk][nt], acc[mt][nt], 0, 0, 0);
  }

  if (isKV) {
    const int z = bid / 80;
    #pragma unroll
    for (int mt = 0; mt < 4; ++mt)
      #pragma unroll
      for (int nt = 0; nt < 4; ++nt)
        #pragma unroll
        for (int r = 0; r < 4; ++r) {
          int row = m0 + wr * 64 + mt * 16 + 4 * g + r;   // [0,1280)
          int col = n0 + wc * 64 + nt * 16 + l15;         // [0,1024)
          unsigned short hv = f2b(acc[mt][nt][r]);
          if (z == 0) {
            kb[(size_t)row * 1024 + col] = hv;
          } else {
            int bc = row / 160, e = row - bc * 160;       // h = col>>6, d = col&63
            vt[((size_t)(bc * 16 + (col >> 6)) * 64 + (col & 63)) * 192 + e] = hv;
          }
        }
  } else {
    // LDS-staged coalesced bf16 epilogue, non-temporal (C never re-read from L2 usefully)
    __syncthreads();
    unsigned short* Cl = (unsigned short*)smem;
    #pragma unroll
    for (int mt = 0; mt < 4; ++mt)
      #pragma unroll
      for (int nt = 0; nt < 4; ++nt)
        #pragma unroll
        for (int r = 0; r < 4; ++r)
          Cl[(wr * 64 + mt * 16 + 4 * g + r) * 128 + wc * 64 + nt * 16 + l15] = f2b(acc[mt][nt][r]);
    __syncthreads();
    #pragma unroll
    for (int j = 0; j < 8; ++j) {
      int ch = j * 256 + tid;
      int row = ch >> 4, sl = ch & 15;
      __builtin_nontemporal_store(*(const short8*)(Cl + row * 128 + sl * 8),
          (short8*)(qb + (size_t)(m0 + row) * 1024 + n0 + sl * 8));
    }
  }
}

// ---------------- O-projection GEMM: fp32 out + bias + bf16 residual ----------------
// A = qb (attn out, bf16), Bt = Wo^T bf16, resid = hsb (hs bf16), out = d_out fp32.
// Non-temporal resid load + C store keep the L2 for the A/B panels.
__global__ __launch_bounds__(256, 2) void k_gemm_o(const unsigned short* __restrict__ A,
                                                   const unsigned short* __restrict__ Bt,
                                                   float* __restrict__ Cout,
                                                   const float* __restrict__ bias,
                                                   const unsigned short* __restrict__ residb) {
  __shared__ __align__(16) char smem[32768];
  char* As = smem;
  char* Bs = smem + 16384;
  const int tid = threadIdx.x;
  const int lane = tid & 63;
  const int l15 = lane & 15;
  const int g = lane >> 4;
  const int wv = tid >> 6;
  const int wr = wv >> 1, wc = wv & 1;
  const int bid = blockIdx.x;
  const int m0 = ((bid >> 6) * 8 + (bid & 7)) * 128;
  const int n0 = ((bid >> 3) & 7) * 128;

  f32x4 acc[4][4];
  #pragma unroll
  for (int i = 0; i < 4; ++i)
    #pragma unroll
    for (int j = 0; j < 4; ++j) acc[i][j] = (f32x4){0.f, 0.f, 0.f, 0.f};

  for (int t = 0; t < 16; ++t) {
    __syncthreads();
    #pragma unroll
    for (int is = 0; is < 4; ++is) {
      int ch = is * 256 + tid;
      int row = ch >> 3, j = ch & 7;
      int sj = (j ^ (row & 7)) * 8;
      gl_lds16(A  + (size_t)(m0 + row) * 1024 + t * 64 + sj, As + ch * 16);
      gl_lds16(Bt + (size_t)(n0 + row) * 1024 + t * 64 + sj, Bs + ch * 16);
    }
    __syncthreads();
    short8 af[2][4], bf[2][4];
    #pragma unroll
    for (int kk = 0; kk < 2; ++kk)
      #pragma unroll
      for (int mt = 0; mt < 4; ++mt) {
        af[kk][mt] = *(const short8*)(As + (wr * 64 + mt * 16 + l15) * 128 + ((kk * 64 + g * 16) ^ ((l15 & 7) << 4)));
        bf[kk][mt] = *(const short8*)(Bs + (wc * 64 + mt * 16 + l15) * 128 + ((kk * 64 + g * 16) ^ ((l15 & 7) << 4)));
      }
    #pragma unroll
    for (int kk = 0; kk < 2; ++kk)
      #pragma unroll
      for (int mt = 0; mt < 4; ++mt)
        #pragma unroll
        for (int nt = 0; nt < 4; ++nt)
          acc[mt][nt] = __builtin_amdgcn_mfma_f32_16x16x32_bf16(af[kk][mt], bf[kk][nt], acc[mt][nt], 0, 0, 0);
  }

  #pragma unroll
  for (int mt = 0; mt < 4; ++mt)
    #pragma unroll
    for (int nt = 0; nt < 4; ++nt)
      #pragma unroll
      for (int r = 0; r < 4; ++r) {
        size_t row = (size_t)(m0 + wr * 64 + mt * 16 + 4 * g + r);
        int col = n0 + wc * 64 + nt * 16 + l15;
        size_t idx = row * 1024 + col;
        unsigned short rh = __builtin_nontemporal_load(residb + idx);
        __builtin_nontemporal_store(acc[mt][nt][r] + bias[col] + b2f(rh), Cout + idx);
      }
}

// ---------------- fused decomposing attention (in-place on qb) ----------------
// grid (S/64, H, B=2); block 256 = 4 waves; wave w = component c (bc = c*2 + b).
// No Q/K/V LDS staging (L2-resident); wp applied AFTER PV; one barrier per strip.
// IN-PLACE: output written over the same qb rows the strip already consumed.
__global__ __launch_bounds__(256, 2) void k_attn(unsigned short* __restrict__ Qb,
                                                 const unsigned short* __restrict__ Kb,
                                                 const unsigned short* __restrict__ Vt) {
  __shared__ __align__(16) char smem[22528];
  float* pooled = (float*)(smem + 21504);   // [4][16][4] f32
  const int tid = threadIdx.x, lane = tid & 63, wv = tid >> 6;
  const int g = lane >> 4, l15 = lane & 15;
  const int s0 = blockIdx.x * 64;
  const int h = blockIdx.y;
  const int b = blockIdx.z;
  const int bc = wv * 2 + b;
  const float scale = 0.125f;

  unsigned short* Qp = Qb + ((size_t)bc * Sm + s0) * Dm + h * 64;
  const unsigned short* Kp = Kb + (size_t)bc * Em * Dm + h * 64;
  const unsigned short* Vp = Vt + ((size_t)bc * Hm + h) * (64 * 192);
  char* Pw = smem + wv * 5376;              // [16 rows][336B]

  #pragma unroll 1
  for (int st = 0; st < 4; ++st) {
    // ---- QK^T: fragments direct from global ----
    short8 qf[2];
    #pragma unroll
    for (int kk = 0; kk < 2; ++kk)
      qf[kk] = *(const short8*)(Qp + (size_t)(st * 16 + l15) * Dm + kk * 32 + g * 8);
    f32x4 sc[10];
    #pragma unroll
    for (int et = 0; et < 10; ++et) {
      sc[et] = (f32x4){0.f, 0.f, 0.f, 0.f};
      #pragma unroll
      for (int kk = 0; kk < 2; ++kk) {
        short8 kf = *(const short8*)(Kp + (size_t)(et * 16 + l15) * Dm + kk * 32 + g * 8);
        sc[et] = __builtin_amdgcn_mfma_f32_16x16x32_bf16(qf[kk], kf, sc[et], 0, 0, 0);
      }
    }
    // ---- pooled mean + row softmax numerators (rows s = st*16 + 4g + r) ----
    float rs4[4];
    #pragma unroll
    for (int r = 0; r < 4; ++r) {
      float v = 0.f;
      #pragma unroll
      for (int et = 0; et < 10; ++et) v += sc[et][r];
      v += __shfl_xor(v, 1); v += __shfl_xor(v, 2); v += __shfl_xor(v, 4); v += __shfl_xor(v, 8);
      if (l15 == 0) pooled[(st * 16 + 4 * g + r) * 4 + wv] = v * (scale / 160.f);
      float mx = sc[0][r];
      #pragma unroll
      for (int et = 1; et < 10; ++et) mx = fmaxf(mx, sc[et][r]);
      mx = fmaxf(mx, __shfl_xor(mx, 1)); mx = fmaxf(mx, __shfl_xor(mx, 2));
      mx = fmaxf(mx, __shfl_xor(mx, 4)); mx = fmaxf(mx, __shfl_xor(mx, 8));
      float rs = 0.f;
      #pragma unroll
      for (int et = 0; et < 10; ++et) {
        float p = __expf((sc[et][r] - mx) * scale);
        rs += p;
        *(unsigned short*)(Pw + (4 * g + r) * 336 + (et * 16 + l15) * 2) = f2b(p);
      }
      rs += __shfl_xor(rs, 1); rs += __shfl_xor(rs, 2); rs += __shfl_xor(rs, 4); rs += __shfl_xor(rs, 8);
      rs4[r] = rs;
    }
    // ---- PV (P from per-wave LDS transpose, V^T direct from global) ----
    f32x4 oa[4];
    #pragma unroll
    for (int dt = 0; dt < 4; ++dt) oa[dt] = (f32x4){0.f, 0.f, 0.f, 0.f};
    #pragma unroll
    for (int k5 = 0; k5 < 5; ++k5) {
      short8 pf = *(const short8*)(Pw + l15 * 336 + k5 * 64 + g * 16);
      #pragma unroll
      for (int dt = 0; dt < 4; ++dt) {
        short8 vf = *(const short8*)(Vp + (size_t)(dt * 16 + l15) * 192 + k5 * 32 + g * 8);
        oa[dt] = __builtin_amdgcn_mfma_f32_16x16x32_bf16(pf, vf, oa[dt], 0, 0, 0);
      }
    }
    __syncthreads();   // all waves have written pooled[st]
    // ---- component softmax rescale + store (in-place over this strip's Q rows) ----
    #pragma unroll
    for (int r = 0; r < 4; ++r) {
      float4 pl = *(const float4*)&pooled[(st * 16 + 4 * g + r) * 4];
      float m3 = fmaxf(fmaxf(pl.x, pl.y), fmaxf(pl.z, pl.w));
      float ssum = __expf(pl.x - m3) + __expf(pl.y - m3) + __expf(pl.z - m3) + __expf(pl.w - m3);
      float mine = (wv == 0) ? pl.x : (wv == 1) ? pl.y : (wv == 2) ? pl.z : pl.w;
      float srw = __expf(mine - m3) / (ssum * rs4[r]);
      #pragma unroll
      for (int dt = 0; dt < 4; ++dt)
        Qp[(size_t)(st * 16 + 4 * g + r) * Dm + dt * 16 + l15] = f2b(oa[dt][r] * srw);
    }
  }
}

extern "C" void kernel_launch(void* const* d_in, const int* in_sizes, int n_in,
                              void* d_out, int out_size, void* d_ws, size_t ws_size,
                              hipStream_t stream) {
  const float* hs  = (const float*)d_in[0];
  const float* ehs = (const float*)d_in[1];
  const float* Wq  = (const float*)d_in[2];
  const float* Wk  = (const float*)d_in[3];
  const float* Wv  = (const float*)d_in[4];
  const float* Wo  = (const float*)d_in[5];
  const float* bo  = (const float*)d_in[6];
  char* ws = (char*)d_ws;
  unsigned short* hsb = (unsigned short*)(ws + OFF_HSB);   // hs bf16 (stays live for O resid)
  unsigned short* wt  = (unsigned short*)(ws + OFF_WT);
  unsigned short* qb  = (unsigned short*)(ws + OFF_QB);    // Q, then attn-out (in-place)
  unsigned short* kb  = (unsigned short*)(ws + OFF_KB);
  unsigned short* vt  = (unsigned short*)(ws + OFF_VT);
  unsigned short* eb  = (unsigned short*)(ws + OFF_EHSB);

  hipLaunchKernelGGL(k_prep, dim3(7424), dim3(256), 0, stream, ehs, eb, hs, hsb, Wq, Wk, Wv, Wo, wt);
  hipLaunchKernelGGL(k_gemm_qkv, dim3(2208), dim3(256), 0, stream, hsb, eb, wt, qb, kb, vt);
  hipLaunchKernelGGL(k_attn, dim3(64, 16, 2), dim3(256), 0, stream, qb, kb, vt);
  hipLaunchKernelGGL(k_gemm_o, dim3(2048), dim3(256), 0, stream, qb, wt + 3 * 1048576, (float*)d_out, bo, hsb);
}

// Round 11
// 334.201 us; speedup vs baseline: 1.0424x; 1.0424x over previous
//
#include <hip/hip_runtime.h>
#include <stdint.h>

typedef __attribute__((ext_vector_type(8))) short short8;
typedef __attribute__((ext_vector_type(4))) float f32x4;
typedef __attribute__((ext_vector_type(4))) unsigned short us4;

#define DI __device__ __forceinline__

static constexpr int Dm = 1024;   // hidden dim
static constexpr int Sm = 4096;   // latent tokens
static constexpr int Em = 160;    // encoder tokens
static constexpr int Hm = 16;     // heads

// workspace layout (bytes)
static constexpr size_t OFF_HSB  = 0;           // hs bf16 [8*4096][1024] (stays live: O-proj resid)
static constexpr size_t OFF_WT   = 67108864;    // 4x Wt bf16 [1024][1024] (transposed: [N][K])
static constexpr size_t OFF_QB   = 75497472;    // Q bf16 [8*4096][1024]; attn overwrites IN-PLACE
static constexpr size_t OFF_KB   = 142606336;   // K bf16 [8*160][1024]
static constexpr size_t OFF_VT   = 147849216;   // V^T bf16 [8][16][64][192]
static constexpr size_t OFF_EHSB = 150994944;   // ehs bf16 [8*160][1024]

DI unsigned short f2b(float f) {
  union { float f; unsigned u; } x; x.f = f;
  unsigned r = x.u + 0x7fffu + ((x.u >> 16) & 1u);
  return (unsigned short)(r >> 16);
}

DI float b2f(unsigned short h) {
  union { unsigned u; float f; } x; x.u = ((unsigned)h) << 16; return x.f;
}

DI void gl_lds16(const void* g, void* l) {
  __builtin_amdgcn_global_load_lds(
      (const __attribute__((address_space(1))) unsigned int*)g,
      (__attribute__((address_space(3))) unsigned int*)l, 16, 0, 0);
}

// ---------------- prep: W transpose+cvt || ehs cvt || hs cvt (one launch) ----------------
__global__ void k_prep(const float* __restrict__ ehs, unsigned short* __restrict__ eb,
                       const float* __restrict__ hs, unsigned short* __restrict__ hsb,
                       const float* __restrict__ W0, const float* __restrict__ W1,
                       const float* __restrict__ W2, const float* __restrict__ W3,
                       unsigned short* __restrict__ Wt) {
  __shared__ float t[32][33];
  const int bid = blockIdx.x, tid = threadIdx.x;
  if (bid < 4096) {
    const int bz = bid >> 10, rest = bid & 1023, by = rest >> 5, bx = rest & 31;
    const float* W = (bz == 0) ? W0 : (bz == 1) ? W1 : (bz == 2) ? W2 : W3;
    unsigned short* o = Wt + (size_t)bz * 1048576;
    const int tx = tid & 31, ty = tid >> 5;
    const int n = bx * 32 + tx, k0 = by * 32;
    #pragma unroll
    for (int j = ty; j < 32; j += 8) t[j][tx] = W[(size_t)(k0 + j) * 1024 + n];
    __syncthreads();
    #pragma unroll
    for (int j = ty; j < 32; j += 8)
      o[(size_t)(bx * 32 + j) * 1024 + k0 + tx] = f2b(t[tx][j]);
  } else if (bid < 5376) {
    const int i = (bid - 4096) * 256 + tid;
    float4 v = ((const float4*)ehs)[i];
    us4 o = { f2b(v.x), f2b(v.y), f2b(v.z), f2b(v.w) };
    *(us4*)(eb + (size_t)i * 4) = o;
  } else {
    for (int i = (bid - 5376) * 256 + tid; i < 8388608; i += 2048 * 256) {
      float4 v = ((const float4*)hs)[i];
      us4 o = { f2b(v.x), f2b(v.y), f2b(v.z), f2b(v.w) };
      *(us4*)(hsb + (size_t)i * 4) = o;
    }
  }
}

// ---------------- fused Q + K + V projection GEMM (one launch) ----------------
// bid < 160 : kv blocks; bid >= 160: Q blocks (m97-class 128x128 body, co-residency
// decode). Q epilogue: LDS-staged coalesced bf16, non-temporal (full 64B sectors).
// __launch_bounds__(256,3): 3 blocks/CU (96KB LDS, ~170 VGPR budget -> no spill)
// for latency hiding of the per-K-step vmcnt drain.
__global__ __launch_bounds__(256, 3) void k_gemm_qkv(const unsigned short* __restrict__ hsb,
                                                     const unsigned short* __restrict__ eb,
                                                     const unsigned short* __restrict__ Wt,
                                                     unsigned short* __restrict__ qb,
                                                     unsigned short* __restrict__ kb,
                                                     unsigned short* __restrict__ vt) {
  __shared__ __align__(16) char smem[32768];
  char* As = smem;
  char* Bs = smem + 16384;
  const int bid = blockIdx.x, tid = threadIdx.x;
  const int lane = tid & 63;
  const int l15 = lane & 15;
  const int g = lane >> 4;
  const int wv = tid >> 6;
  const int wr = wv >> 1, wc = wv & 1;

  const bool isKV = (bid < 160);
  int m0, n0;
  const unsigned short *Ap, *Bt;
  if (isKV) {
    const int z = bid / 80, rr = bid - z * 80;
    m0 = (rr % 10) * 128; n0 = (rr / 10) * 128;
    Ap = eb; Bt = Wt + (size_t)(1 + z) * 1048576;
  } else {
    const int q = bid - 160;
    m0 = ((q >> 6) * 8 + (q & 7)) * 128;
    n0 = ((q >> 3) & 7) * 128;
    Ap = hsb; Bt = Wt;
  }

  f32x4 acc[4][4];
  #pragma unroll
  for (int i = 0; i < 4; ++i)
    #pragma unroll
    for (int j = 0; j < 4; ++j) acc[i][j] = (f32x4){0.f, 0.f, 0.f, 0.f};

  for (int t = 0; t < 16; ++t) {
    __syncthreads();
    #pragma unroll
    for (int is = 0; is < 4; ++is) {
      int ch = is * 256 + tid;
      int row = ch >> 3, j = ch & 7;
      int sj = (j ^ (row & 7)) * 8;
      gl_lds16(Ap + (size_t)(m0 + row) * 1024 + t * 64 + sj, As + ch * 16);
      gl_lds16(Bt + (size_t)(n0 + row) * 1024 + t * 64 + sj, Bs + ch * 16);
    }
    __syncthreads();
    short8 af[2][4], bf[2][4];
    #pragma unroll
    for (int kk = 0; kk < 2; ++kk)
      #pragma unroll
      for (int mt = 0; mt < 4; ++mt) {
        af[kk][mt] = *(const short8*)(As + (wr * 64 + mt * 16 + l15) * 128 + ((kk * 64 + g * 16) ^ ((l15 & 7) << 4)));
        bf[kk][mt] = *(const short8*)(Bs + (wc * 64 + mt * 16 + l15) * 128 + ((kk * 64 + g * 16) ^ ((l15 & 7) << 4)));
      }
    #pragma unroll
    for (int kk = 0; kk < 2; ++kk)
      #pragma unroll
      for (int mt = 0; mt < 4; ++mt)
        #pragma unroll
        for (int nt = 0; nt < 4; ++nt)
          acc[mt][nt] = __builtin_amdgcn_mfma_f32_16x16x32_bf16(af[kk][mt], bf[kk][nt], acc[mt][nt], 0, 0, 0);
  }

  if (isKV) {
    const int z = bid / 80;
    #pragma unroll
    for (int mt = 0; mt < 4; ++mt)
      #pragma unroll
      for (int nt = 0; nt < 4; ++nt)
        #pragma unroll
        for (int r = 0; r < 4; ++r) {
          int row = m0 + wr * 64 + mt * 16 + 4 * g + r;   // [0,1280)
          int col = n0 + wc * 64 + nt * 16 + l15;         // [0,1024)
          unsigned short hv = f2b(acc[mt][nt][r]);
          if (z == 0) {
            kb[(size_t)row * 1024 + col] = hv;
          } else {
            int bc = row / 160, e = row - bc * 160;       // h = col>>6, d = col&63
            vt[((size_t)(bc * 16 + (col >> 6)) * 64 + (col & 63)) * 192 + e] = hv;
          }
        }
  } else {
    __syncthreads();
    unsigned short* Cl = (unsigned short*)smem;
    #pragma unroll
    for (int mt = 0; mt < 4; ++mt)
      #pragma unroll
      for (int nt = 0; nt < 4; ++nt)
        #pragma unroll
        for (int r = 0; r < 4; ++r)
          Cl[(wr * 64 + mt * 16 + 4 * g + r) * 128 + wc * 64 + nt * 16 + l15] = f2b(acc[mt][nt][r]);
    __syncthreads();
    #pragma unroll
    for (int j = 0; j < 8; ++j) {
      int ch = j * 256 + tid;
      int row = ch >> 4, sl = ch & 15;
      __builtin_nontemporal_store(*(const short8*)(Cl + row * 128 + sl * 8),
          (short8*)(qb + (size_t)(m0 + row) * 1024 + n0 + sl * 8));
    }
  }
}

// ---------------- O-projection GEMM: fp32 out + bias + bf16 residual ----------------
// Plain C stores (L2 write-back merges the 64B segments into full lines; R10's
// nt store caused 132->172MB write amplification). nt resid LOAD kept (streaming,
// no pollution). __launch_bounds__(256,3) for latency hiding.
__global__ __launch_bounds__(256, 3) void k_gemm_o(const unsigned short* __restrict__ A,
                                                   const unsigned short* __restrict__ Bt,
                                                   float* __restrict__ Cout,
                                                   const float* __restrict__ bias,
                                                   const unsigned short* __restrict__ residb) {
  __shared__ __align__(16) char smem[32768];
  char* As = smem;
  char* Bs = smem + 16384;
  const int tid = threadIdx.x;
  const int lane = tid & 63;
  const int l15 = lane & 15;
  const int g = lane >> 4;
  const int wv = tid >> 6;
  const int wr = wv >> 1, wc = wv & 1;
  const int bid = blockIdx.x;
  const int m0 = ((bid >> 6) * 8 + (bid & 7)) * 128;
  const int n0 = ((bid >> 3) & 7) * 128;

  f32x4 acc[4][4];
  #pragma unroll
  for (int i = 0; i < 4; ++i)
    #pragma unroll
    for (int j = 0; j < 4; ++j) acc[i][j] = (f32x4){0.f, 0.f, 0.f, 0.f};

  for (int t = 0; t < 16; ++t) {
    __syncthreads();
    #pragma unroll
    for (int is = 0; is < 4; ++is) {
      int ch = is * 256 + tid;
      int row = ch >> 3, j = ch & 7;
      int sj = (j ^ (row & 7)) * 8;
      gl_lds16(A  + (size_t)(m0 + row) * 1024 + t * 64 + sj, As + ch * 16);
      gl_lds16(Bt + (size_t)(n0 + row) * 1024 + t * 64 + sj, Bs + ch * 16);
    }
    __syncthreads();
    short8 af[2][4], bf[2][4];
    #pragma unroll
    for (int kk = 0; kk < 2; ++kk)
      #pragma unroll
      for (int mt = 0; mt < 4; ++mt) {
        af[kk][mt] = *(const short8*)(As + (wr * 64 + mt * 16 + l15) * 128 + ((kk * 64 + g * 16) ^ ((l15 & 7) << 4)));
        bf[kk][mt] = *(const short8*)(Bs + (wc * 64 + mt * 16 + l15) * 128 + ((kk * 64 + g * 16) ^ ((l15 & 7) << 4)));
      }
    #pragma unroll
    for (int kk = 0; kk < 2; ++kk)
      #pragma unroll
      for (int mt = 0; mt < 4; ++mt)
        #pragma unroll
        for (int nt = 0; nt < 4; ++nt)
          acc[mt][nt] = __builtin_amdgcn_mfma_f32_16x16x32_bf16(af[kk][mt], bf[kk][nt], acc[mt][nt], 0, 0, 0);
  }

  #pragma unroll
  for (int mt = 0; mt < 4; ++mt)
    #pragma unroll
    for (int nt = 0; nt < 4; ++nt)
      #pragma unroll
      for (int r = 0; r < 4; ++r) {
        size_t row = (size_t)(m0 + wr * 64 + mt * 16 + 4 * g + r);
        int col = n0 + wc * 64 + nt * 16 + l15;
        size_t idx = row * 1024 + col;
        unsigned short rh = __builtin_nontemporal_load(residb + idx);
        Cout[idx] = acc[mt][nt][r] + bias[col] + b2f(rh);
      }
}

// ---------------- fused decomposing attention (in-place on qb) ----------------
__global__ __launch_bounds__(256, 2) void k_attn(unsigned short* __restrict__ Qb,
                                                 const unsigned short* __restrict__ Kb,
                                                 const unsigned short* __restrict__ Vt) {
  __shared__ __align__(16) char smem[22528];
  float* pooled = (float*)(smem + 21504);   // [4][16][4] f32
  const int tid = threadIdx.x, lane = tid & 63, wv = tid >> 6;
  const int g = lane >> 4, l15 = lane & 15;
  const int s0 = blockIdx.x * 64;
  const int h = blockIdx.y;
  const int b = blockIdx.z;
  const int bc = wv * 2 + b;
  const float scale = 0.125f;

  unsigned short* Qp = Qb + ((size_t)bc * Sm + s0) * Dm + h * 64;
  const unsigned short* Kp = Kb + (size_t)bc * Em * Dm + h * 64;
  const unsigned short* Vp = Vt + ((size_t)bc * Hm + h) * (64 * 192);
  char* Pw = smem + wv * 5376;              // [16 rows][336B]

  #pragma unroll 1
  for (int st = 0; st < 4; ++st) {
    short8 qf[2];
    #pragma unroll
    for (int kk = 0; kk < 2; ++kk)
      qf[kk] = *(const short8*)(Qp + (size_t)(st * 16 + l15) * Dm + kk * 32 + g * 8);
    f32x4 sc[10];
    #pragma unroll
    for (int et = 0; et < 10; ++et) {
      sc[et] = (f32x4){0.f, 0.f, 0.f, 0.f};
      #pragma unroll
      for (int kk = 0; kk < 2; ++kk) {
        short8 kf = *(const short8*)(Kp + (size_t)(et * 16 + l15) * Dm + kk * 32 + g * 8);
        sc[et] = __builtin_amdgcn_mfma_f32_16x16x32_bf16(qf[kk], kf, sc[et], 0, 0, 0);
      }
    }
    float rs4[4];
    #pragma unroll
    for (int r = 0; r < 4; ++r) {
      float v = 0.f;
      #pragma unroll
      for (int et = 0; et < 10; ++et) v += sc[et][r];
      v += __shfl_xor(v, 1); v += __shfl_xor(v, 2); v += __shfl_xor(v, 4); v += __shfl_xor(v, 8);
      if (l15 == 0) pooled[(st * 16 + 4 * g + r) * 4 + wv] = v * (scale / 160.f);
      float mx = sc[0][r];
      #pragma unroll
      for (int et = 1; et < 10; ++et) mx = fmaxf(mx, sc[et][r]);
      mx = fmaxf(mx, __shfl_xor(mx, 1)); mx = fmaxf(mx, __shfl_xor(mx, 2));
      mx = fmaxf(mx, __shfl_xor(mx, 4)); mx = fmaxf(mx, __shfl_xor(mx, 8));
      float rs = 0.f;
      #pragma unroll
      for (int et = 0; et < 10; ++et) {
        float p = __expf((sc[et][r] - mx) * scale);
        rs += p;
        *(unsigned short*)(Pw + (4 * g + r) * 336 + (et * 16 + l15) * 2) = f2b(p);
      }
      rs += __shfl_xor(rs, 1); rs += __shfl_xor(rs, 2); rs += __shfl_xor(rs, 4); rs += __shfl_xor(rs, 8);
      rs4[r] = rs;
    }
    f32x4 oa[4];
    #pragma unroll
    for (int dt = 0; dt < 4; ++dt) oa[dt] = (f32x4){0.f, 0.f, 0.f, 0.f};
    #pragma unroll
    for (int k5 = 0; k5 < 5; ++k5) {
      short8 pf = *(const short8*)(Pw + l15 * 336 + k5 * 64 + g * 16);
      #pragma unroll
      for (int dt = 0; dt < 4; ++dt) {
        short8 vf = *(const short8*)(Vp + (size_t)(dt * 16 + l15) * 192 + k5 * 32 + g * 8);
        oa[dt] = __builtin_amdgcn_mfma_f32_16x16x32_bf16(pf, vf, oa[dt], 0, 0, 0);
      }
    }
    __syncthreads();
    #pragma unroll
    for (int r = 0; r < 4; ++r) {
      float4 pl = *(const float4*)&pooled[(st * 16 + 4 * g + r) * 4];
      float m3 = fmaxf(fmaxf(pl.x, pl.y), fmaxf(pl.z, pl.w));
      float ssum = __expf(pl.x - m3) + __expf(pl.y - m3) + __expf(pl.z - m3) + __expf(pl.w - m3);
      float mine = (wv == 0) ? pl.x : (wv == 1) ? pl.y : (wv == 2) ? pl.z : pl.w;
      float srw = __expf(mine - m3) / (ssum * rs4[r]);
      #pragma unroll
      for (int dt = 0; dt < 4; ++dt)
        Qp[(size_t)(st * 16 + 4 * g + r) * Dm + dt * 16 + l15] = f2b(oa[dt][r] * srw);
    }
  }
}

extern "C" void kernel_launch(void* const* d_in, const int* in_sizes, int n_in,
                              void* d_out, int out_size, void* d_ws, size_t ws_size,
                              hipStream_t stream) {
  const float* hs  = (const float*)d_in[0];
  const float* ehs = (const float*)d_in[1];
  const float* Wq  = (const float*)d_in[2];
  const float* Wk  = (const float*)d_in[3];
  const float* Wv  = (const float*)d_in[4];
  const float* Wo  = (const float*)d_in[5];
  const float* bo  = (const float*)d_in[6];
  char* ws = (char*)d_ws;
  unsigned short* hsb = (unsigned short*)(ws + OFF_HSB);   // hs bf16 (stays live for O resid)
  unsigned short* wt  = (unsigned short*)(ws + OFF_WT);
  unsigned short* qb  = (unsigned short*)(ws + OFF_QB);    // Q, then attn-out (in-place)
  unsigned short* kb  = (unsigned short*)(ws + OFF_KB);
  unsigned short* vt  = (unsigned short*)(ws + OFF_VT);
  unsigned short* eb  = (unsigned short*)(ws + OFF_EHSB);

  hipLaunchKernelGGL(k_prep, dim3(7424), dim3(256), 0, stream, ehs, eb, hs, hsb, Wq, Wk, Wv, Wo, wt);
  hipLaunchKernelGGL(k_gemm_qkv, dim3(2208), dim3(256), 0, stream, hsb, eb, wt, qb, kb, vt);
  hipLaunchKernelGGL(k_attn, dim3(64, 16, 2), dim3(256), 0, stream, qb, kb, vt);
  hipLaunchKernelGGL(k_gemm_o, dim3(2048), dim3(256), 0, stream, qb, wt + 3 * 1048576, (float*)d_out, bo, hsb);
}

// Round 12
// 330.379 us; speedup vs baseline: 1.0544x; 1.0116x over previous
//
#include <hip/hip_runtime.h>
#include <stdint.h>

typedef __attribute__((ext_vector_type(8))) short short8;
typedef __attribute__((ext_vector_type(4))) float f32x4;
typedef __attribute__((ext_vector_type(4))) unsigned short us4;

#define DI __device__ __forceinline__

static constexpr int Dm = 1024;   // hidden dim
static constexpr int Sm = 4096;   // latent tokens
static constexpr int Em = 160;    // encoder tokens
static constexpr int Hm = 16;     // heads

// workspace layout (bytes)
static constexpr size_t OFF_HSB  = 0;           // hs bf16 [8*4096][1024] (stays live: O-proj resid)
static constexpr size_t OFF_WT   = 67108864;    // 4x Wt bf16 [1024][1024] (transposed: [N][K])
static constexpr size_t OFF_QB   = 75497472;    // Q bf16 [8*4096][1024]; attn overwrites IN-PLACE
static constexpr size_t OFF_KB   = 142606336;   // K bf16 [8*160][1024]
static constexpr size_t OFF_KBAR = 145227776;   // k-bar bf16 [8][16][64] (mean K row per bc,h)
static constexpr size_t OFF_VT   = 147849216;   // V^T bf16 [8][16][64][192]
static constexpr size_t OFF_EHSB = 150994944;   // ehs bf16 [8*160][1024]

DI unsigned short f2b(float f) {
  union { float f; unsigned u; } x; x.f = f;
  unsigned r = x.u + 0x7fffu + ((x.u >> 16) & 1u);
  return (unsigned short)(r >> 16);
}

DI float b2f(unsigned short h) {
  union { unsigned u; float f; } x; x.u = ((unsigned)h) << 16; return x.f;
}

DI void gl_lds16(const void* g, void* l) {
  __builtin_amdgcn_global_load_lds(
      (const __attribute__((address_space(1))) unsigned int*)g,
      (__attribute__((address_space(3))) unsigned int*)l, 16, 0, 0);
}

// ---------------- prep: W transpose+cvt || ehs cvt || hs cvt (one launch) ----------------
__global__ void k_prep(const float* __restrict__ ehs, unsigned short* __restrict__ eb,
                       const float* __restrict__ hs, unsigned short* __restrict__ hsb,
                       const float* __restrict__ W0, const float* __restrict__ W1,
                       const float* __restrict__ W2, const float* __restrict__ W3,
                       unsigned short* __restrict__ Wt) {
  __shared__ float t[32][33];
  const int bid = blockIdx.x, tid = threadIdx.x;
  if (bid < 4096) {
    const int bz = bid >> 10, rest = bid & 1023, by = rest >> 5, bx = rest & 31;
    const float* W = (bz == 0) ? W0 : (bz == 1) ? W1 : (bz == 2) ? W2 : W3;
    unsigned short* o = Wt + (size_t)bz * 1048576;
    const int tx = tid & 31, ty = tid >> 5;
    const int n = bx * 32 + tx, k0 = by * 32;
    #pragma unroll
    for (int j = ty; j < 32; j += 8) t[j][tx] = W[(size_t)(k0 + j) * 1024 + n];
    __syncthreads();
    #pragma unroll
    for (int j = ty; j < 32; j += 8)
      o[(size_t)(bx * 32 + j) * 1024 + k0 + tx] = f2b(t[tx][j]);
  } else if (bid < 5376) {
    const int i = (bid - 4096) * 256 + tid;
    float4 v = ((const float4*)ehs)[i];
    us4 o = { f2b(v.x), f2b(v.y), f2b(v.z), f2b(v.w) };
    *(us4*)(eb + (size_t)i * 4) = o;
  } else {
    for (int i = (bid - 5376) * 256 + tid; i < 8388608; i += 2048 * 256) {
      float4 v = ((const float4*)hs)[i];
      us4 o = { f2b(v.x), f2b(v.y), f2b(v.z), f2b(v.w) };
      *(us4*)(hsb + (size_t)i * 4) = o;
    }
  }
}

// ---------------- fused Q + K + V projection GEMM (one launch) ----------------
__global__ __launch_bounds__(256, 3) void k_gemm_qkv(const unsigned short* __restrict__ hsb,
                                                     const unsigned short* __restrict__ eb,
                                                     const unsigned short* __restrict__ Wt,
                                                     unsigned short* __restrict__ qb,
                                                     unsigned short* __restrict__ kb,
                                                     unsigned short* __restrict__ vt) {
  __shared__ __align__(16) char smem[32768];
  char* As = smem;
  char* Bs = smem + 16384;
  const int bid = blockIdx.x, tid = threadIdx.x;
  const int lane = tid & 63;
  const int l15 = lane & 15;
  const int g = lane >> 4;
  const int wv = tid >> 6;
  const int wr = wv >> 1, wc = wv & 1;

  const bool isKV = (bid < 160);
  int m0, n0;
  const unsigned short *Ap, *Bt;
  if (isKV) {
    const int z = bid / 80, rr = bid - z * 80;
    m0 = (rr % 10) * 128; n0 = (rr / 10) * 128;
    Ap = eb; Bt = Wt + (size_t)(1 + z) * 1048576;
  } else {
    const int q = bid - 160;
    m0 = ((q >> 6) * 8 + (q & 7)) * 128;
    n0 = ((q >> 3) & 7) * 128;
    Ap = hsb; Bt = Wt;
  }

  f32x4 acc[4][4];
  #pragma unroll
  for (int i = 0; i < 4; ++i)
    #pragma unroll
    for (int j = 0; j < 4; ++j) acc[i][j] = (f32x4){0.f, 0.f, 0.f, 0.f};

  for (int t = 0; t < 16; ++t) {
    __syncthreads();
    #pragma unroll
    for (int is = 0; is < 4; ++is) {
      int ch = is * 256 + tid;
      int row = ch >> 3, j = ch & 7;
      int sj = (j ^ (row & 7)) * 8;
      gl_lds16(Ap + (size_t)(m0 + row) * 1024 + t * 64 + sj, As + ch * 16);
      gl_lds16(Bt + (size_t)(n0 + row) * 1024 + t * 64 + sj, Bs + ch * 16);
    }
    __syncthreads();
    short8 af[2][4], bf[2][4];
    #pragma unroll
    for (int kk = 0; kk < 2; ++kk)
      #pragma unroll
      for (int mt = 0; mt < 4; ++mt) {
        af[kk][mt] = *(const short8*)(As + (wr * 64 + mt * 16 + l15) * 128 + ((kk * 64 + g * 16) ^ ((l15 & 7) << 4)));
        bf[kk][mt] = *(const short8*)(Bs + (wc * 64 + mt * 16 + l15) * 128 + ((kk * 64 + g * 16) ^ ((l15 & 7) << 4)));
      }
    #pragma unroll
    for (int kk = 0; kk < 2; ++kk)
      #pragma unroll
      for (int mt = 0; mt < 4; ++mt)
        #pragma unroll
        for (int nt = 0; nt < 4; ++nt)
          acc[mt][nt] = __builtin_amdgcn_mfma_f32_16x16x32_bf16(af[kk][mt], bf[kk][nt], acc[mt][nt], 0, 0, 0);
  }

  if (isKV) {
    const int z = bid / 80;
    #pragma unroll
    for (int mt = 0; mt < 4; ++mt)
      #pragma unroll
      for (int nt = 0; nt < 4; ++nt)
        #pragma unroll
        for (int r = 0; r < 4; ++r) {
          int row = m0 + wr * 64 + mt * 16 + 4 * g + r;   // [0,1280)
          int col = n0 + wc * 64 + nt * 16 + l15;         // [0,1024)
          unsigned short hv = f2b(acc[mt][nt][r]);
          if (z == 0) {
            kb[(size_t)row * 1024 + col] = hv;
          } else {
            int bc = row / 160, e = row - bc * 160;       // h = col>>6, d = col&63
            vt[((size_t)(bc * 16 + (col >> 6)) * 64 + (col & 63)) * 192 + e] = hv;
          }
        }
  } else {
    __syncthreads();
    unsigned short* Cl = (unsigned short*)smem;
    #pragma unroll
    for (int mt = 0; mt < 4; ++mt)
      #pragma unroll
      for (int nt = 0; nt < 4; ++nt)
        #pragma unroll
        for (int r = 0; r < 4; ++r)
          Cl[(wr * 64 + mt * 16 + 4 * g + r) * 128 + wc * 64 + nt * 16 + l15] = f2b(acc[mt][nt][r]);
    __syncthreads();
    #pragma unroll
    for (int j = 0; j < 8; ++j) {
      int ch = j * 256 + tid;
      int row = ch >> 4, sl = ch & 15;
      __builtin_nontemporal_store(*(const short8*)(Cl + row * 128 + sl * 8),
          (short8*)(qb + (size_t)(m0 + row) * 1024 + n0 + sl * 8));
    }
  }
}

// ---------------- k-bar: mean K row per (bc,h): kbar[bc][h][d] = mean_e kb[bc*160+e][h*64+d] ----------------
// grid 128 = bc*16+h, 64 threads (d). Coalesced 128B per e-row.
__global__ void k_kbar(const unsigned short* __restrict__ kb, unsigned short* __restrict__ kbar) {
  const int bh = blockIdx.x, d = threadIdx.x;
  const int bc = bh >> 4, h = bh & 15;
  const unsigned short* src = kb + ((size_t)bc * Em) * Dm + h * 64 + d;
  float s = 0.f;
  #pragma unroll 4
  for (int e = 0; e < Em; ++e) s += b2f(src[(size_t)e * Dm]);
  kbar[(size_t)bh * 64 + d] = f2b(s * (1.f / 160.f));
}

// ---------------- O-projection GEMM: fp32 out + bias + bf16 residual ----------------
__global__ __launch_bounds__(256, 3) void k_gemm_o(const unsigned short* __restrict__ A,
                                                   const unsigned short* __restrict__ Bt,
                                                   float* __restrict__ Cout,
                                                   const float* __restrict__ bias,
                                                   const unsigned short* __restrict__ residb) {
  __shared__ __align__(16) char smem[32768];
  char* As = smem;
  char* Bs = smem + 16384;
  const int tid = threadIdx.x;
  const int lane = tid & 63;
  const int l15 = lane & 15;
  const int g = lane >> 4;
  const int wv = tid >> 6;
  const int wr = wv >> 1, wc = wv & 1;
  const int bid = blockIdx.x;
  const int m0 = ((bid >> 6) * 8 + (bid & 7)) * 128;
  const int n0 = ((bid >> 3) & 7) * 128;

  f32x4 acc[4][4];
  #pragma unroll
  for (int i = 0; i < 4; ++i)
    #pragma unroll
    for (int j = 0; j < 4; ++j) acc[i][j] = (f32x4){0.f, 0.f, 0.f, 0.f};

  for (int t = 0; t < 16; ++t) {
    __syncthreads();
    #pragma unroll
    for (int is = 0; is < 4; ++is) {
      int ch = is * 256 + tid;
      int row = ch >> 3, j = ch & 7;
      int sj = (j ^ (row & 7)) * 8;
      gl_lds16(A  + (size_t)(m0 + row) * 1024 + t * 64 + sj, As + ch * 16);
      gl_lds16(Bt + (size_t)(n0 + row) * 1024 + t * 64 + sj, Bs + ch * 16);
    }
    __syncthreads();
    short8 af[2][4], bf[2][4];
    #pragma unroll
    for (int kk = 0; kk < 2; ++kk)
      #pragma unroll
      for (int mt = 0; mt < 4; ++mt) {
        af[kk][mt] = *(const short8*)(As + (wr * 64 + mt * 16 + l15) * 128 + ((kk * 64 + g * 16) ^ ((l15 & 7) << 4)));
        bf[kk][mt] = *(const short8*)(Bs + (wc * 64 + mt * 16 + l15) * 128 + ((kk * 64 + g * 16) ^ ((l15 & 7) << 4)));
      }
    #pragma unroll
    for (int kk = 0; kk < 2; ++kk)
      #pragma unroll
      for (int mt = 0; mt < 4; ++mt)
        #pragma unroll
        for (int nt = 0; nt < 4; ++nt)
          acc[mt][nt] = __builtin_amdgcn_mfma_f32_16x16x32_bf16(af[kk][mt], bf[kk][nt], acc[mt][nt], 0, 0, 0);
  }

  #pragma unroll
  for (int mt = 0; mt < 4; ++mt)
    #pragma unroll
    for (int nt = 0; nt < 4; ++nt)
      #pragma unroll
      for (int r = 0; r < 4; ++r) {
        size_t row = (size_t)(m0 + wr * 64 + mt * 16 + 4 * g + r);
        int col = n0 + wc * 64 + nt * 16 + l15;
        size_t idx = row * 1024 + col;
        unsigned short rh = __builtin_nontemporal_load(residb + idx);
        Cout[idx] = acc[mt][nt][r] + bias[col] + b2f(rh);
      }
}

// ---------------- fused decomposing attention v4 (in-place on qb) ----------------
// Softmax algebraics: pooled mean = q . kbar via 2 extra MFMAs with kbar replicated
// across B columns (every lane gets pooled for its 4 rows -> no mean-reduction);
// no max-subtraction (|scores*scale| ~ <= 6, exp cannot overflow; softmax is
// ratio-invariant). Remaining cross-lane work: one 16-lane rs reduction per row.
__global__ __launch_bounds__(256, 2) void k_attn(unsigned short* __restrict__ Qb,
                                                 const unsigned short* __restrict__ Kb,
                                                 const unsigned short* __restrict__ Vt,
                                                 const unsigned short* __restrict__ Kbar) {
  __shared__ __align__(16) char smem[22528];
  float* pooled = (float*)(smem + 21504);   // [4 strips][16 rows][4 comps] f32
  const int tid = threadIdx.x, lane = tid & 63, wv = tid >> 6;
  const int g = lane >> 4, l15 = lane & 15;
  const int s0 = blockIdx.x * 64;
  const int h = blockIdx.y;
  const int b = blockIdx.z;
  const int bc = wv * 2 + b;
  const float scale = 0.125f;

  unsigned short* Qp = Qb + ((size_t)bc * Sm + s0) * Dm + h * 64;
  const unsigned short* Kp = Kb + (size_t)bc * Em * Dm + h * 64;
  const unsigned short* Vp = Vt + ((size_t)bc * Hm + h) * (64 * 192);
  char* Pw = smem + wv * 5376;              // [16 rows][336B]

  // kbar fragment, replicated across the 16 B-columns (independent of l15)
  const unsigned short* kbp = Kbar + (size_t)(bc * 16 + h) * 64;
  short8 kbf[2];
  #pragma unroll
  for (int kk = 0; kk < 2; ++kk)
    kbf[kk] = *(const short8*)(kbp + kk * 32 + g * 8);

  #pragma unroll 1
  for (int st = 0; st < 4; ++st) {
    // ---- QK^T + pooled (q.kbar) ----
    short8 qf[2];
    #pragma unroll
    for (int kk = 0; kk < 2; ++kk)
      qf[kk] = *(const short8*)(Qp + (size_t)(st * 16 + l15) * Dm + kk * 32 + g * 8);
    f32x4 scb = (f32x4){0.f, 0.f, 0.f, 0.f};
    #pragma unroll
    for (int kk = 0; kk < 2; ++kk)
      scb = __builtin_amdgcn_mfma_f32_16x16x32_bf16(qf[kk], kbf[kk], scb, 0, 0, 0);
    f32x4 sc[10];
    #pragma unroll
    for (int et = 0; et < 10; ++et) {
      sc[et] = (f32x4){0.f, 0.f, 0.f, 0.f};
      #pragma unroll
      for (int kk = 0; kk < 2; ++kk) {
        short8 kf = *(const short8*)(Kp + (size_t)(et * 16 + l15) * Dm + kk * 32 + g * 8);
        sc[et] = __builtin_amdgcn_mfma_f32_16x16x32_bf16(qf[kk], kf, sc[et], 0, 0, 0);
      }
    }
    // ---- softmax numerators (no max-subtract) + rs reduce; publish pooled ----
    float rs4[4];
    #pragma unroll
    for (int r = 0; r < 4; ++r) {
      if (l15 == 0) pooled[(st * 16 + 4 * g + r) * 4 + wv] = scb[r] * scale;
      float rs = 0.f;
      #pragma unroll
      for (int et = 0; et < 10; ++et) {
        float p = __expf(sc[et][r] * scale);
        rs += p;
        *(unsigned short*)(Pw + (4 * g + r) * 336 + (et * 16 + l15) * 2) = f2b(p);
      }
      rs += __shfl_xor(rs, 1); rs += __shfl_xor(rs, 2); rs += __shfl_xor(rs, 4); rs += __shfl_xor(rs, 8);
      rs4[r] = rs;
    }
    // ---- PV ----
    f32x4 oa[4];
    #pragma unroll
    for (int dt = 0; dt < 4; ++dt) oa[dt] = (f32x4){0.f, 0.f, 0.f, 0.f};
    #pragma unroll
    for (int k5 = 0; k5 < 5; ++k5) {
      short8 pf = *(const short8*)(Pw + l15 * 336 + k5 * 64 + g * 16);
      #pragma unroll
      for (int dt = 0; dt < 4; ++dt) {
        short8 vf = *(const short8*)(Vp + (size_t)(dt * 16 + l15) * 192 + k5 * 32 + g * 8);
        oa[dt] = __builtin_amdgcn_mfma_f32_16x16x32_bf16(pf, vf, oa[dt], 0, 0, 0);
      }
    }
    __syncthreads();   // all waves have written pooled[st]
    // ---- component softmax rescale + store (in-place) ----
    #pragma unroll
    for (int r = 0; r < 4; ++r) {
      float4 pl = *(const float4*)&pooled[(st * 16 + 4 * g + r) * 4];
      float m3 = fmaxf(fmaxf(pl.x, pl.y), fmaxf(pl.z, pl.w));
      float ssum = __expf(pl.x - m3) + __expf(pl.y - m3) + __expf(pl.z - m3) + __expf(pl.w - m3);
      float mine = (wv == 0) ? pl.x : (wv == 1) ? pl.y : (wv == 2) ? pl.z : pl.w;
      float srw = __expf(mine - m3) / (ssum * rs4[r]);
      #pragma unroll
      for (int dt = 0; dt < 4; ++dt)
        Qp[(size_t)(st * 16 + 4 * g + r) * Dm + dt * 16 + l15] = f2b(oa[dt][r] * srw);
    }
  }
}

extern "C" void kernel_launch(void* const* d_in, const int* in_sizes, int n_in,
                              void* d_out, int out_size, void* d_ws, size_t ws_size,
                              hipStream_t stream) {
  const float* hs  = (const float*)d_in[0];
  const float* ehs = (const float*)d_in[1];
  const float* Wq  = (const float*)d_in[2];
  const float* Wk  = (const float*)d_in[3];
  const float* Wv  = (const float*)d_in[4];
  const float* Wo  = (const float*)d_in[5];
  const float* bo  = (const float*)d_in[6];
  char* ws = (char*)d_ws;
  unsigned short* hsb  = (unsigned short*)(ws + OFF_HSB);
  unsigned short* wt   = (unsigned short*)(ws + OFF_WT);
  unsigned short* qb   = (unsigned short*)(ws + OFF_QB);
  unsigned short* kb   = (unsigned short*)(ws + OFF_KB);
  unsigned short* kbar = (unsigned short*)(ws + OFF_KBAR);
  unsigned short* vt   = (unsigned short*)(ws + OFF_VT);
  unsigned short* eb   = (unsigned short*)(ws + OFF_EHSB);

  hipLaunchKernelGGL(k_prep, dim3(7424), dim3(256), 0, stream, ehs, eb, hs, hsb, Wq, Wk, Wv, Wo, wt);
  hipLaunchKernelGGL(k_gemm_qkv, dim3(2208), dim3(256), 0, stream, hsb, eb, wt, qb, kb, vt);
  hipLaunchKernelGGL(k_kbar, dim3(128), dim3(64), 0, stream, kb, kbar);
  hipLaunchKernelGGL(k_attn, dim3(64, 16, 2), dim3(256), 0, stream, qb, kb, vt, kbar);
  hipLaunchKernelGGL(k_gemm_o, dim3(2048), dim3(256), 0, stream, qb, wt + 3 * 1048576, (float*)d_out, bo, hsb);
}